// Round 12
// baseline (185.141 us; speedup 1.0000x reference)
//
#include <hip/hip_runtime.h>

#define NN 128
#define NEGF -1e30f
#define DELTA 1.5e-5f

// ---- wave64 inclusive prefix-sum via DPP (6 dependent VALU ops) ----
__device__ __forceinline__ float dpp_scan_add(float x) {
    int v;
    v = __builtin_amdgcn_update_dpp(0, __float_as_int(x), 0x111, 0xf, 0xf, true);
    x += __int_as_float(v);
    v = __builtin_amdgcn_update_dpp(0, __float_as_int(x), 0x112, 0xf, 0xf, true);
    x += __int_as_float(v);
    v = __builtin_amdgcn_update_dpp(0, __float_as_int(x), 0x114, 0xf, 0xf, true);
    x += __int_as_float(v);
    v = __builtin_amdgcn_update_dpp(0, __float_as_int(x), 0x118, 0xf, 0xf, true);
    x += __int_as_float(v);
    v = __builtin_amdgcn_update_dpp(0, __float_as_int(x), 0x142, 0xa, 0xf, true);
    x += __int_as_float(v);
    v = __builtin_amdgcn_update_dpp(0, __float_as_int(x), 0x143, 0xc, 0xf, true);
    x += __int_as_float(v);
    return x;   // lane l holds sum over lanes 0..l
}

// ---- wave64 max-scan via DPP; lane 63 holds the global max (slow path) ----
__device__ __forceinline__ float dpp_scan_max(float x) {
    const int negi = __float_as_int(NEGF);
    int v;
    v = __builtin_amdgcn_update_dpp(negi, __float_as_int(x), 0x111, 0xf, 0xf, false);
    x = fmaxf(x, __int_as_float(v));
    v = __builtin_amdgcn_update_dpp(negi, __float_as_int(x), 0x112, 0xf, 0xf, false);
    x = fmaxf(x, __int_as_float(v));
    v = __builtin_amdgcn_update_dpp(negi, __float_as_int(x), 0x114, 0xf, 0xf, false);
    x = fmaxf(x, __int_as_float(v));
    v = __builtin_amdgcn_update_dpp(negi, __float_as_int(x), 0x118, 0xf, 0xf, false);
    x = fmaxf(x, __int_as_float(v));
    v = __builtin_amdgcn_update_dpp(negi, __float_as_int(x), 0x142, 0xa, 0xf, false);
    x = fmaxf(x, __int_as_float(v));
    v = __builtin_amdgcn_update_dpp(negi, __float_as_int(x), 0x143, 0xc, 0xf, false);
    x = fmaxf(x, __int_as_float(v));
    return x;
}

__device__ __forceinline__ float bcast63(float x) {
    return __int_as_float(__builtin_amdgcn_readlane(__float_as_int(x), 63));
}

// row_ror:N butterfly helpers (rotation within each 16-lane DPP row)
__device__ __forceinline__ float dpp_ror_f(float x, int ctrl_unused) { return x; }
#define ROR_MERGE(CTRL)                                                          \
    {                                                                            \
        float ov = __int_as_float(__builtin_amdgcn_update_dpp(                   \
            0, __float_as_int(val), (CTRL), 0xf, 0xf, false));                   \
        int oc = __builtin_amdgcn_update_dpp(0, cand, (CTRL), 0xf, 0xf, false);  \
        bool take = (ov > val) || (ov == val && oc < cand);                      \
        val = take ? ov : val;                                                   \
        cand = take ? oc : cand;                                                 \
    }

// ---------------- K0: sigmoid table ----------------
__global__ void k_sig(const float* __restrict__ P, float* __restrict__ sigS) {
    int i = blockIdx.x * blockDim.x + threadIdx.x;
    if (i < NN * NN) {
        double p = (double)P[i];
        sigS[i] = (float)(1.0 / (1.0 + exp(-p)));
    }
}

// -------- fused: order sampling (batched rescans) + pipelined build tail ---
// LDS swizzle: S[r][c] lives at S[r*128 + (c ^ (r & 31))]
__launch_bounds__(256)
__global__ void k_fused(const float* __restrict__ sigS,
                        const float* __restrict__ uniforms,
                        const float* __restrict__ G,
                        float* __restrict__ out0,
                        float* __restrict__ orderF, int D) {
    __shared__ float S[NN * NN];                // 64KB swizzled sigmoid table
    __shared__ unsigned char T8[4][NN * NN];    // 64KB: one 16KB tile per dag
    __shared__ int ordS[4 * NN];                // 2KB: per-wave order
    const int tid = threadIdx.x;

    // stage sigP -> LDS (swizzled) and zero all 4 tiles; ONE barrier
    for (int k = 0; k < 16; ++k) {
        int idx4 = (k * 256 + tid) * 4;
        int r = idx4 >> 7, cb = idx4 & 127;
        float4 v = *reinterpret_cast<const float4*>(&sigS[idx4]);
        int x = r & 31;
        float4 w;
        switch (x & 3) {
            case 0: w = v; break;
            case 1: w = make_float4(v.y, v.x, v.w, v.z); break;
            case 2: w = make_float4(v.z, v.w, v.x, v.y); break;
            default: w = make_float4(v.w, v.z, v.y, v.x); break;
        }
        *reinterpret_cast<float4*>(&S[r * 128 + ((cb ^ x) & ~3)]) = w;
    }
    {
        uint4 z = make_uint4(0, 0, 0, 0);
        #pragma unroll
        for (int k = 0; k < 16; ++k)
            reinterpret_cast<uint4*>(&T8[0][0])[k * 256 + tid] = z;
    }
    __syncthreads();

    const int lane = tid & 63;
    const int wv = tid >> 6;
    const int dag = blockIdx.x * 4 + wv;

    if (dag < D) {
        const int i0 = 2 * lane, i1 = 2 * lane + 1;
        const int x0 = i0 & 31, x1 = i1 & 31;
        const int q0 = x0 & 3, q1 = x1 & 3;
        float2 uu = *reinterpret_cast<const float2*>(&uniforms[dag * NN + i0]);

        unsigned long long mlo = ~0ull, mhi = ~0ull;

        // initial row max + holder column
        float rm0 = NEGF, rm1 = NEGF;
        int rc0 = 0, rc1 = 0;
        for (int k = 0; k < 32; ++k) {
            int cb = 4 * ((k + lane) & 31);
            float4 a = *reinterpret_cast<const float4*>(&S[i0 * 128 + (cb ^ (x0 & ~3))]);
            float4 b = *reinterpret_cast<const float4*>(&S[i1 * 128 + (cb ^ (x1 & ~3))]);
            if (a.x > rm0) { rm0 = a.x; rc0 = cb | (0 ^ q0); }
            if (a.y > rm0) { rm0 = a.y; rc0 = cb | (1 ^ q0); }
            if (a.z > rm0) { rm0 = a.z; rc0 = cb | (2 ^ q0); }
            if (a.w > rm0) { rm0 = a.w; rc0 = cb | (3 ^ q0); }
            if (b.x > rm1) { rm1 = b.x; rc1 = cb | (0 ^ q1); }
            if (b.y > rm1) { rm1 = b.y; rc1 = cb | (1 ^ q1); }
            if (b.z > rm1) { rm1 = b.z; rc1 = cb | (2 ^ q1); }
            if (b.w > rm1) { rm1 = b.w; rc1 = cb | (3 ^ q1); }
        }

        float e0 = __expf(1.0f - rm0);   // 0 marks inactive row
        float e1 = __expf(1.0f - rm1);

        const int g16 = lane >> 4, s16 = lane & 15;

        #pragma unroll 1
        for (int t = 0; t < NN; ++t) {
            float usel = (t & 1) ? uu.y : uu.x;
            float ut = __int_as_float(__builtin_amdgcn_readlane(__float_as_int(usel), t >> 1));

            float incl = dpp_scan_add(e0 + e1);
            float T = bcast63(incl);
            float thr = ut * T;
            float cum1 = incl, cum0 = incl - e1;

            bool a0 = (e0 != 0.0f), a1 = (e1 != 0.0f);
            bool c0 = a0 && (cum0 >= thr);
            bool c1 = a1 && (cum1 >= thr);
            float mg = DELTA * T;
            bool amb = (a0 && fabsf(cum0 - thr) <= mg) || (a1 && fabsf(cum1 - thr) <= mg);

            unsigned long long b0 = __ballot(c0), b1 = __ballot(c1);
            unsigned long long ba = __ballot(amb);
            int lastActive = mhi ? (127 - __clzll(mhi)) : (63 - __clzll(mlo));

            int idx;
            if (__builtin_expect(ba != 0ull, 0)) {
                // ---- slow path: bit-faithful numpy-f32 emulation ----
                float l0 = 1.0f - rm0, l1v = 1.0f - rm1;
                float lvi = fmaxf(a0 ? l0 : NEGF, a1 ? l1v : NEGF);
                float lv = bcast63(dpp_scan_max(lvi));
                float f0 = a0 ? expf(l0 - lv) : 0.0f;
                float f1 = a1 ? expf(l1v - lv) : 0.0f;
                // numpy pairwise-8 accumulator sum
                int mm = lane & 3;
                float s0 = __shfl(f0, mm), s1 = __shfl(f1, mm);
                #pragma unroll
                for (int k2 = 1; k2 < 16; ++k2) {
                    s0 += __shfl(f0, mm + 4 * k2);
                    s1 += __shfl(f1, mm + 4 * k2);
                }
                float A00 = __shfl(s0, 0), A01 = __shfl(s0, 1), A02 = __shfl(s0, 2), A03 = __shfl(s0, 3);
                float A10 = __shfl(s1, 0), A11 = __shfl(s1, 1), A12 = __shfl(s1, 2), A13 = __shfl(s1, 3);
                float tot = ((A00 + A10) + (A01 + A11)) + ((A02 + A12) + (A03 + A13));
                float s = 0.0f;
                int pick = -1;
                for (int j = 0; j < NN; ++j) {
                    float ej = __shfl((j & 1) ? f1 : f0, j >> 1);
                    float pj = ej / tot;
                    s += pj;
                    bool aj = (j < 64) ? ((mlo >> j) & 1ull) : ((mhi >> (j - 64)) & 1ull);
                    if (pick < 0 && aj && s >= ut) pick = j;
                }
                idx = (pick >= 0) ? pick : lastActive;
            } else {
                int f0i = b0 ? 2 * (__ffsll(b0) - 1) : 999;
                int f1i = b1 ? 2 * (__ffsll(b1) - 1) + 1 : 999;
                idx = min(f0i, f1i);
                if (idx == 999) idx = lastActive;
            }

            if (lane == 0) ordS[wv * NN + t] = idx;

            if (idx < 64) mlo &= ~(1ull << idx);
            else          mhi &= ~(1ull << (idx - 64));
            if (idx == i0) e0 = 0.0f;
            if (idx == i1) e1 = 0.0f;
            a0 = (e0 != 0.0f); a1 = (e1 != 0.0f);

            // rescan rows whose tracked max-holder column was removed,
            // batched 4 rows per pass (16 lanes per row, row_ror butterfly)
            unsigned long long mA = __ballot(a0 && (rc0 == idx));
            unsigned long long mB = __ballot(a1 && (rc1 == idx));

            while (mA | mB) {
                int rws[4];
                #pragma unroll
                for (int gi = 0; gi < 4; ++gi) {
                    int rw = -1;
                    if (mA)      { int L = __ffsll(mA) - 1; mA &= mA - 1; rw = 2 * L; }
                    else if (mB) { int L = __ffsll(mB) - 1; mB &= mB - 1; rw = 2 * L + 1; }
                    rws[gi] = rw;
                }
                int myrow = (g16 == 0) ? rws[0] : (g16 == 1) ? rws[1]
                          : (g16 == 2) ? rws[2] : rws[3];

                float val = NEGF;
                int cand = 999;
                if (myrow >= 0) {
                    int xm = myrow & 31;
                    #pragma unroll
                    for (int k = 0; k < 8; ++k) {
                        int c = s16 + 16 * k;
                        bool act = (c < 64) ? ((mlo >> c) & 1ull)
                                            : ((mhi >> (c - 64)) & 1ull);
                        float v = act ? S[myrow * 128 + (c ^ xm)] : NEGF;
                        if (v > val) { val = v; cand = c; }
                    }
                }
                // (max, min-col) butterfly within each 16-lane group
                ROR_MERGE(0x121);   // row_ror:1
                ROR_MERGE(0x122);   // row_ror:2
                ROR_MERGE(0x124);   // row_ror:4
                ROR_MERGE(0x128);   // row_ror:8

                #pragma unroll
                for (int gi = 0; gi < 4; ++gi) {
                    if (rws[gi] >= 0) {
                        float m2 = __int_as_float(__builtin_amdgcn_readlane(
                                       __float_as_int(val), gi * 16));
                        int nc = __builtin_amdgcn_readlane(cand, gi * 16);
                        int L = rws[gi] >> 1;
                        if ((rws[gi] & 1) == 0) {
                            if (lane == L) { rm0 = m2; rc0 = nc; e0 = __expf(1.0f - m2); }
                        } else {
                            if (lane == L) { rm1 = m2; rc1 = nc; e1 = __expf(1.0f - m2); }
                        }
                    }
                }
            }
        }
    }
    __syncthreads();

    // ---- write order output (coalesced) ----
    #pragma unroll
    for (int k = 0; k < 2; ++k) {
        int i = k * 256 + tid;
        int dg = blockIdx.x * 4 + (i >> 7);
        if (dg < D) orderF[(size_t)blockIdx.x * 512 + i] = (float)ordS[i];
    }

    // ---- build tail: 5 iterations, dump(w-1) overlapped under compute(w) --
    for (int w = 0; w <= 4; ++w) {
        if (w >= 1) {
            const int dPrev = blockIdx.x * 4 + (w - 1);
            if (dPrev < D) {
                const unsigned char* Tp = T8[w - 1];
                float* od = out0 + (size_t)dPrev * NN * NN;
                #pragma unroll
                for (int k = 0; k < 16; ++k) {
                    int base = k * 1024 + tid * 4;
                    int i = base >> 7, j = base & 127;
                    const uchar4 v = *reinterpret_cast<const uchar4*>(&Tp[i * NN + (j ^ (i & 124))]);
                    float4 o;
                    o.x = (float)v.x; o.y = (float)v.y; o.z = (float)v.z; o.w = (float)v.w;
                    *reinterpret_cast<float4*>(&od[base]) = o;
                }
            }
        }
        if (w < 4) {
            const int d = blockIdx.x * 4 + w;
            if (d < D) {
                unsigned char* Tw = T8[w];
                const float* G0 = G + (size_t)d * 2 * NN * NN;
                const float* G1 = G0 + NN * NN;
                const int* pw = &ordS[w * NN];

                for (int base = 0; base < 8192; base += 2048) {
                    float u0[8], u1[8], sg[8];
                    int rr8[8], cc8[8];
                    bool ok[8];
                    #pragma unroll
                    for (int j = 0; j < 8; ++j) {
                        int k = base + j * 256 + tid;
                        ok[j] = (k < 8128);
                        if (ok[j]) {
                            float fr = sqrtf(8.0f * (float)k + 1.0f);
                            int r = (int)((1.0f + fr) * 0.5f);
                            if (r * (r - 1) / 2 > k) --r;
                            if ((r + 1) * r / 2 <= k) ++r;
                            int c = k - r * (r - 1) / 2;
                            rr8[j] = r; cc8[j] = c;
                            int idx = r * NN + c;
                            u0[j] = G0[idx];
                            u1[j] = G1[idx];
                            int prr = pw[r], pcc = pw[c];
                            sg[j] = S[prr * 128 + (pcc ^ (prr & 31))];
                        }
                    }
                    #pragma unroll
                    for (int j = 0; j < 8; ++j) {
                        if (ok[j]) {
                            int prr = pw[rr8[j]], pcc = pw[cc8[j]];
                            // la+g0 >= l1+g1  <=>  sg*B >= (1-sg)*A
                            float A = -__logf(u0[j] + 1e-10f) + 1e-10f;
                            float B = -__logf(u1[j] + 1e-10f) + 1e-10f;
                            Tw[pcc * NN + (prr ^ (pcc & 124))] = (sg[j] * B >= (1.0f - sg[j]) * A) ? 1 : 0;
                        }
                    }
                }
            }
        }
        __syncthreads();
    }
}

extern "C" void kernel_launch(void* const* d_in, const int* in_sizes, int n_in,
                              void* d_out, int out_size, void* d_ws, size_t ws_size,
                              hipStream_t stream) {
    const float* P        = (const float*)d_in[0];
    const float* uniforms = (const float*)d_in[1];
    const float* G        = (const float*)d_in[2];
    const int D = in_sizes[1] / NN;

    float* out0   = (float*)d_out;
    float* orderF = out0 + (size_t)D * NN * NN;
    float* sigS   = (float*)d_ws;   // 64KB

    k_sig<<<(NN * NN + 255) / 256, 256, 0, stream>>>(P, sigS);
    k_fused<<<(D + 3) / 4, 256, 0, stream>>>(sigS, uniforms, G, out0, orderF, D);
}

// Round 13
// 176.616 us; speedup vs baseline: 1.0483x; 1.0483x over previous
//
#include <hip/hip_runtime.h>

#define NN 128
#define NEGF -1e30f
#define DELTA 1.5e-5f
#define Q 8

// ---- wave64 inclusive prefix-sum via DPP (6 dependent VALU ops) ----
__device__ __forceinline__ float dpp_scan_add(float x) {
    int v;
    v = __builtin_amdgcn_update_dpp(0, __float_as_int(x), 0x111, 0xf, 0xf, true);
    x += __int_as_float(v);
    v = __builtin_amdgcn_update_dpp(0, __float_as_int(x), 0x112, 0xf, 0xf, true);
    x += __int_as_float(v);
    v = __builtin_amdgcn_update_dpp(0, __float_as_int(x), 0x114, 0xf, 0xf, true);
    x += __int_as_float(v);
    v = __builtin_amdgcn_update_dpp(0, __float_as_int(x), 0x118, 0xf, 0xf, true);
    x += __int_as_float(v);
    v = __builtin_amdgcn_update_dpp(0, __float_as_int(x), 0x142, 0xa, 0xf, true);
    x += __int_as_float(v);
    v = __builtin_amdgcn_update_dpp(0, __float_as_int(x), 0x143, 0xc, 0xf, true);
    x += __int_as_float(v);
    return x;   // lane l holds sum over lanes 0..l
}

// ---- wave64 max-scan via DPP; lane 63 holds the global max (slow path) ----
__device__ __forceinline__ float dpp_scan_max(float x) {
    const int negi = __float_as_int(NEGF);
    int v;
    v = __builtin_amdgcn_update_dpp(negi, __float_as_int(x), 0x111, 0xf, 0xf, false);
    x = fmaxf(x, __int_as_float(v));
    v = __builtin_amdgcn_update_dpp(negi, __float_as_int(x), 0x112, 0xf, 0xf, false);
    x = fmaxf(x, __int_as_float(v));
    v = __builtin_amdgcn_update_dpp(negi, __float_as_int(x), 0x114, 0xf, 0xf, false);
    x = fmaxf(x, __int_as_float(v));
    v = __builtin_amdgcn_update_dpp(negi, __float_as_int(x), 0x118, 0xf, 0xf, false);
    x = fmaxf(x, __int_as_float(v));
    v = __builtin_amdgcn_update_dpp(negi, __float_as_int(x), 0x142, 0xa, 0xf, false);
    x = fmaxf(x, __int_as_float(v));
    v = __builtin_amdgcn_update_dpp(negi, __float_as_int(x), 0x143, 0xc, 0xf, false);
    x = fmaxf(x, __int_as_float(v));
    return x;
}

__device__ __forceinline__ float bcast63(float x) {
    return __int_as_float(__builtin_amdgcn_readlane(__float_as_int(x), 63));
}

// ---------------- K0: sigmoid + per-row descending rank-sort (transposed) --
// PRg[rank*128 + row] = (float_bits(sig) << 32) | col ; rank 0 = row max.
__launch_bounds__(NN)
__global__ void k_sort(const float* __restrict__ P, float* __restrict__ sigS,
                       unsigned long long* __restrict__ PRg) {
    __shared__ float row[NN];
    const int r = blockIdx.x, c = threadIdx.x;
    double pv = (double)P[r * NN + c];
    float s = (float)(1.0 / (1.0 + exp(-pv)));
    sigS[r * NN + c] = s;
    row[c] = s;
    __syncthreads();
    int rank = 0;
    for (int j = 0; j < NN; ++j) {
        float v = row[j];
        rank += (v > s) || (v == s && j < c);
    }
    PRg[rank * NN + r] = ((unsigned long long)(unsigned)__float_as_int(s) << 32) | (unsigned)c;
}

// -------- fused: sampling with register queues + pipelined build tail ------
__launch_bounds__(256)
__global__ void k_fused(const unsigned long long* __restrict__ PRg,
                        const float* __restrict__ sigS,
                        const float* __restrict__ uniforms,
                        const float* __restrict__ G,
                        float* __restrict__ out0,
                        float* __restrict__ orderF, int D) {
    __shared__ unsigned long long PR[NN * NN];   // 128KB sorted lists; reused as T8 tiles
    __shared__ int ordS[4 * NN];                 // 2KB: per-wave order
    const int tid = threadIdx.x;

    // stage sorted lists -> LDS (straight copy, transposed layout already)
    {
        const uint4* s4 = (const uint4*)PRg;
        uint4* d4 = (uint4*)PR;
        #pragma unroll
        for (int k = 0; k < 32; ++k) d4[k * 256 + tid] = s4[k * 256 + tid];
    }
    __syncthreads();

    const int lane = tid & 63;
    const int wv = tid >> 6;
    const int dag = blockIdx.x * 4 + wv;

    if (dag < D) {
        const int i0 = 2 * lane, i1 = 2 * lane + 1;
        float2 uu = *reinterpret_cast<const float2*>(&uniforms[dag * NN + i0]);

        unsigned long long mlo = ~0ull, mhi = ~0ull;

        // per-row register queues: next Q sorted entries (static-indexed)
        float qv0[Q], qv1[Q];
        int qc0[Q], qc1[Q];
        #pragma unroll
        for (int j = 0; j < Q; ++j) {
            unsigned long long e0j = PR[j * NN + i0];
            unsigned long long e1j = PR[j * NN + i1];
            qv0[j] = __int_as_float((int)(e0j >> 32)); qc0[j] = (int)(e0j & 127u);
            qv1[j] = __int_as_float((int)(e1j >> 32)); qc1[j] = (int)(e1j & 127u);
        }
        int pos0 = Q, pos1 = Q;     // next PR rank to load
        int rem0 = Q, rem1 = Q;     // valid entries left in queue

        float rm0 = qv0[0], rm1 = qv1[0];
        float e0 = __expf(1.0f - rm0);   // 0 marks inactive row
        float e1 = __expf(1.0f - rm1);

        #pragma unroll 1
        for (int t = 0; t < NN; ++t) {
            float usel = (t & 1) ? uu.y : uu.x;
            float ut = __int_as_float(__builtin_amdgcn_readlane(__float_as_int(usel), t >> 1));

            float incl = dpp_scan_add(e0 + e1);
            float T = bcast63(incl);
            float thr = ut * T;
            float cum1 = incl, cum0 = incl - e1;

            bool a0 = (e0 != 0.0f), a1 = (e1 != 0.0f);
            bool c0 = a0 && (cum0 >= thr);
            bool c1 = a1 && (cum1 >= thr);
            float mg = DELTA * T;
            bool amb = (a0 && fabsf(cum0 - thr) <= mg) || (a1 && fabsf(cum1 - thr) <= mg);

            unsigned long long b0 = __ballot(c0), b1 = __ballot(c1);
            unsigned long long ba = __ballot(amb);
            int lastActive = mhi ? (127 - __clzll(mhi)) : (63 - __clzll(mlo));

            int idx;
            if (__builtin_expect(ba != 0ull, 0)) {
                // ---- slow path: bit-faithful numpy-f32 emulation ----
                float l0 = 1.0f - rm0, l1v = 1.0f - rm1;
                float lvi = fmaxf(a0 ? l0 : NEGF, a1 ? l1v : NEGF);
                float lv = bcast63(dpp_scan_max(lvi));
                float f0 = a0 ? expf(l0 - lv) : 0.0f;
                float f1 = a1 ? expf(l1v - lv) : 0.0f;
                // numpy pairwise-8 accumulator sum
                int mm = lane & 3;
                float s0 = __shfl(f0, mm), s1 = __shfl(f1, mm);
                #pragma unroll
                for (int k2 = 1; k2 < 16; ++k2) {
                    s0 += __shfl(f0, mm + 4 * k2);
                    s1 += __shfl(f1, mm + 4 * k2);
                }
                float A00 = __shfl(s0, 0), A01 = __shfl(s0, 1), A02 = __shfl(s0, 2), A03 = __shfl(s0, 3);
                float A10 = __shfl(s1, 0), A11 = __shfl(s1, 1), A12 = __shfl(s1, 2), A13 = __shfl(s1, 3);
                float tot = ((A00 + A10) + (A01 + A11)) + ((A02 + A12) + (A03 + A13));
                float s = 0.0f;
                int pick = -1;
                for (int j = 0; j < NN; ++j) {
                    float ej = __shfl((j & 1) ? f1 : f0, j >> 1);
                    float pj = ej / tot;
                    s += pj;
                    bool aj = (j < 64) ? ((mlo >> j) & 1ull) : ((mhi >> (j - 64)) & 1ull);
                    if (pick < 0 && aj && s >= ut) pick = j;
                }
                idx = (pick >= 0) ? pick : lastActive;
            } else {
                int f0i = b0 ? 2 * (__ffsll(b0) - 1) : 999;
                int f1i = b1 ? 2 * (__ffsll(b1) - 1) + 1 : 999;
                idx = min(f0i, f1i);
                if (idx == 999) idx = lastActive;
            }

            if (lane == 0) ordS[wv * NN + t] = idx;

            if (idx < 64) mlo &= ~(1ull << idx);
            else          mhi &= ~(1ull << (idx - 64));
            if (idx == i0) e0 = 0.0f;
            if (idx == i1) e1 = 0.0f;

            // advance row 0 if its head column was just removed
            if (e0 != 0.0f && qc0[0] == idx) {
                for (;;) {
                    #pragma unroll
                    for (int j = 0; j < Q - 1; ++j) { qv0[j] = qv0[j + 1]; qc0[j] = qc0[j + 1]; }
                    if (--rem0 == 0) {
                        #pragma unroll
                        for (int j = 0; j < Q; ++j) {
                            int k = min(pos0 + j, NN - 1);
                            unsigned long long e = PR[k * NN + i0];
                            qv0[j] = __int_as_float((int)(e >> 32));
                            qc0[j] = (int)(e & 127u);
                        }
                        pos0 += Q; rem0 = Q;
                    }
                    int hc = qc0[0];
                    bool act = (hc < 64) ? ((mlo >> hc) & 1ull) : ((mhi >> (hc - 64)) & 1ull);
                    if (act) break;
                }
                rm0 = qv0[0]; e0 = __expf(1.0f - rm0);
            }
            // advance row 1
            if (e1 != 0.0f && qc1[0] == idx) {
                for (;;) {
                    #pragma unroll
                    for (int j = 0; j < Q - 1; ++j) { qv1[j] = qv1[j + 1]; qc1[j] = qc1[j + 1]; }
                    if (--rem1 == 0) {
                        #pragma unroll
                        for (int j = 0; j < Q; ++j) {
                            int k = min(pos1 + j, NN - 1);
                            unsigned long long e = PR[k * NN + i1];
                            qv1[j] = __int_as_float((int)(e >> 32));
                            qc1[j] = (int)(e & 127u);
                        }
                        pos1 += Q; rem1 = Q;
                    }
                    int hc = qc1[0];
                    bool act = (hc < 64) ? ((mlo >> hc) & 1ull) : ((mhi >> (hc - 64)) & 1ull);
                    if (act) break;
                }
                rm1 = qv1[0]; e1 = __expf(1.0f - rm1);
            }
        }
    }
    __syncthreads();   // sampling done; PR space is now dead -> reuse as tiles

    // ---- write order output (coalesced) ----
    #pragma unroll
    for (int k = 0; k < 2; ++k) {
        int i = k * 256 + tid;
        int dg = blockIdx.x * 4 + (i >> 7);
        if (dg < D) orderF[(size_t)blockIdx.x * 512 + i] = (float)ordS[i];
    }

    // ---- zero the 4 tiles (aliasing PR) ----
    unsigned char* T8base = (unsigned char*)PR;
    {
        uint4 z = make_uint4(0, 0, 0, 0);
        #pragma unroll
        for (int k = 0; k < 16; ++k)
            reinterpret_cast<uint4*>(T8base)[k * 256 + tid] = z;
    }
    __syncthreads();

    // ---- build tail: 5 iterations, dump(w-1) overlapped under compute(w) --
    for (int w = 0; w <= 4; ++w) {
        if (w >= 1) {
            const int dPrev = blockIdx.x * 4 + (w - 1);
            if (dPrev < D) {
                const unsigned char* Tp = T8base + (w - 1) * NN * NN;
                float* od = out0 + (size_t)dPrev * NN * NN;
                #pragma unroll
                for (int k = 0; k < 16; ++k) {
                    int base = k * 1024 + tid * 4;
                    int i = base >> 7, j = base & 127;
                    const uchar4 v = *reinterpret_cast<const uchar4*>(&Tp[i * NN + (j ^ (i & 124))]);
                    float4 o;
                    o.x = (float)v.x; o.y = (float)v.y; o.z = (float)v.z; o.w = (float)v.w;
                    *reinterpret_cast<float4*>(&od[base]) = o;
                }
            }
        }
        if (w < 4) {
            const int d = blockIdx.x * 4 + w;
            if (d < D) {
                unsigned char* Tw = T8base + w * NN * NN;
                const float* G0 = G + (size_t)d * 2 * NN * NN;
                const float* G1 = G0 + NN * NN;
                const int* pw = &ordS[w * NN];

                for (int base = 0; base < 8192; base += 2048) {
                    float u0[8], u1[8], sg[8];
                    int rr8[8], cc8[8];
                    bool ok[8];
                    #pragma unroll
                    for (int j = 0; j < 8; ++j) {
                        int k = base + j * 256 + tid;
                        ok[j] = (k < 8128);
                        if (ok[j]) {
                            float fr = sqrtf(8.0f * (float)k + 1.0f);
                            int r = (int)((1.0f + fr) * 0.5f);
                            if (r * (r - 1) / 2 > k) --r;
                            if ((r + 1) * r / 2 <= k) ++r;
                            int c = k - r * (r - 1) / 2;
                            rr8[j] = r; cc8[j] = c;
                            int idx = r * NN + c;
                            u0[j] = G0[idx];
                            u1[j] = G1[idx];
                            sg[j] = sigS[pw[r] * NN + pw[c]];
                        }
                    }
                    #pragma unroll
                    for (int j = 0; j < 8; ++j) {
                        if (ok[j]) {
                            int prr = pw[rr8[j]], pcc = pw[cc8[j]];
                            // la+g0 >= l1+g1  <=>  sg*B >= (1-sg)*A
                            float A = -__logf(u0[j] + 1e-10f) + 1e-10f;
                            float B = -__logf(u1[j] + 1e-10f) + 1e-10f;
                            Tw[pcc * NN + (prr ^ (pcc & 124))] = (sg[j] * B >= (1.0f - sg[j]) * A) ? 1 : 0;
                        }
                    }
                }
            }
        }
        __syncthreads();
    }
}

extern "C" void kernel_launch(void* const* d_in, const int* in_sizes, int n_in,
                              void* d_out, int out_size, void* d_ws, size_t ws_size,
                              hipStream_t stream) {
    const float* P        = (const float*)d_in[0];
    const float* uniforms = (const float*)d_in[1];
    const float* G        = (const float*)d_in[2];
    const int D = in_sizes[1] / NN;

    float* out0   = (float*)d_out;
    float* orderF = out0 + (size_t)D * NN * NN;
    float* sigS   = (float*)d_ws;                                         // 64KB
    unsigned long long* PRg = (unsigned long long*)((char*)d_ws + 65536); // 128KB

    k_sort<<<NN, NN, 0, stream>>>(P, sigS, PRg);
    k_fused<<<(D + 3) / 4, 256, 0, stream>>>(PRg, sigS, uniforms, G, out0, orderF, D);
}

// Round 14
// 153.672 us; speedup vs baseline: 1.2048x; 1.1493x over previous
//
#include <hip/hip_runtime.h>

#define NN 128
#define NEGF -1e30f
#define DELTA 1.5e-5f

// ---- wave64 inclusive prefix-sum via DPP (6 dependent VALU ops) ----
__device__ __forceinline__ float dpp_scan_add(float x) {
    int v;
    v = __builtin_amdgcn_update_dpp(0, __float_as_int(x), 0x111, 0xf, 0xf, true);
    x += __int_as_float(v);
    v = __builtin_amdgcn_update_dpp(0, __float_as_int(x), 0x112, 0xf, 0xf, true);
    x += __int_as_float(v);
    v = __builtin_amdgcn_update_dpp(0, __float_as_int(x), 0x114, 0xf, 0xf, true);
    x += __int_as_float(v);
    v = __builtin_amdgcn_update_dpp(0, __float_as_int(x), 0x118, 0xf, 0xf, true);
    x += __int_as_float(v);
    v = __builtin_amdgcn_update_dpp(0, __float_as_int(x), 0x142, 0xa, 0xf, true);
    x += __int_as_float(v);
    v = __builtin_amdgcn_update_dpp(0, __float_as_int(x), 0x143, 0xc, 0xf, true);
    x += __int_as_float(v);
    return x;   // lane l holds sum over lanes 0..l
}

// ---- wave64 max-scan via DPP; lane 63 holds the global max ----
__device__ __forceinline__ float dpp_scan_max(float x) {
    const int negi = __float_as_int(NEGF);
    int v;
    v = __builtin_amdgcn_update_dpp(negi, __float_as_int(x), 0x111, 0xf, 0xf, false);
    x = fmaxf(x, __int_as_float(v));
    v = __builtin_amdgcn_update_dpp(negi, __float_as_int(x), 0x112, 0xf, 0xf, false);
    x = fmaxf(x, __int_as_float(v));
    v = __builtin_amdgcn_update_dpp(negi, __float_as_int(x), 0x114, 0xf, 0xf, false);
    x = fmaxf(x, __int_as_float(v));
    v = __builtin_amdgcn_update_dpp(negi, __float_as_int(x), 0x118, 0xf, 0xf, false);
    x = fmaxf(x, __int_as_float(v));
    v = __builtin_amdgcn_update_dpp(negi, __float_as_int(x), 0x142, 0xa, 0xf, false);
    x = fmaxf(x, __int_as_float(v));
    v = __builtin_amdgcn_update_dpp(negi, __float_as_int(x), 0x143, 0xc, 0xf, false);
    x = fmaxf(x, __int_as_float(v));
    return x;
}

__device__ __forceinline__ float bcast63(float x) {
    return __int_as_float(__builtin_amdgcn_readlane(__float_as_int(x), 63));
}

// ---------------- K0: sigmoid table ----------------
__global__ void k_sig(const float* __restrict__ P, float* __restrict__ sigS) {
    int i = blockIdx.x * blockDim.x + threadIdx.x;
    if (i < NN * NN) {
        double p = (double)P[i];
        sigS[i] = (float)(1.0 / (1.0 + exp(-p)));
    }
}

// -------- fused: order sampling (trimmed R4 chain) + pipelined build tail --
// LDS swizzle: S[r][c] lives at S[r*128 + (c ^ (r & 31))]
__launch_bounds__(256)
__global__ void k_fused(const float* __restrict__ sigS,
                        const float* __restrict__ uniforms,
                        const float* __restrict__ G,
                        float* __restrict__ out0,
                        float* __restrict__ orderF, int D) {
    __shared__ float S[NN * NN];                // 64KB swizzled sigmoid table
    __shared__ unsigned char T8[4][NN * NN];    // 64KB: one 16KB tile per dag
    __shared__ int ordS[4 * NN];                // 2KB: per-wave order
    const int tid = threadIdx.x;

    // stage sigP -> LDS (swizzled) and zero all 4 tiles; ONE barrier
    for (int k = 0; k < 16; ++k) {
        int idx4 = (k * 256 + tid) * 4;
        int r = idx4 >> 7, cb = idx4 & 127;
        float4 v = *reinterpret_cast<const float4*>(&sigS[idx4]);
        int x = r & 31;
        float4 w;
        switch (x & 3) {
            case 0: w = v; break;
            case 1: w = make_float4(v.y, v.x, v.w, v.z); break;
            case 2: w = make_float4(v.z, v.w, v.x, v.y); break;
            default: w = make_float4(v.w, v.z, v.y, v.x); break;
        }
        *reinterpret_cast<float4*>(&S[r * 128 + ((cb ^ x) & ~3)]) = w;
    }
    {
        uint4 z = make_uint4(0, 0, 0, 0);
        #pragma unroll
        for (int k = 0; k < 16; ++k)
            reinterpret_cast<uint4*>(&T8[0][0])[k * 256 + tid] = z;
    }
    __syncthreads();

    const int lane = tid & 63;
    const int wv = tid >> 6;
    const int dag = blockIdx.x * 4 + wv;

    if (dag < D) {
        const int i0 = 2 * lane, i1 = 2 * lane + 1;
        const int x0 = i0 & 31, x1 = i1 & 31;
        const int q0 = x0 & 3, q1 = x1 & 3;
        float2 uu = *reinterpret_cast<const float2*>(&uniforms[dag * NN + i0]);

        unsigned long long mlo = ~0ull, mhi = ~0ull;

        // initial row max + holder column
        float rm0 = NEGF, rm1 = NEGF;
        int rc0 = 0, rc1 = 0;
        for (int k = 0; k < 32; ++k) {
            int cb = 4 * ((k + lane) & 31);
            float4 a = *reinterpret_cast<const float4*>(&S[i0 * 128 + (cb ^ (x0 & ~3))]);
            float4 b = *reinterpret_cast<const float4*>(&S[i1 * 128 + (cb ^ (x1 & ~3))]);
            if (a.x > rm0) { rm0 = a.x; rc0 = cb | (0 ^ q0); }
            if (a.y > rm0) { rm0 = a.y; rc0 = cb | (1 ^ q0); }
            if (a.z > rm0) { rm0 = a.z; rc0 = cb | (2 ^ q0); }
            if (a.w > rm0) { rm0 = a.w; rc0 = cb | (3 ^ q0); }
            if (b.x > rm1) { rm1 = b.x; rc1 = cb | (0 ^ q1); }
            if (b.y > rm1) { rm1 = b.y; rc1 = cb | (1 ^ q1); }
            if (b.z > rm1) { rm1 = b.z; rc1 = cb | (2 ^ q1); }
            if (b.w > rm1) { rm1 = b.w; rc1 = cb | (3 ^ q1); }
        }

        float e0 = __expf(1.0f - rm0);   // 0 marks inactive row
        float e1 = __expf(1.0f - rm1);

        #pragma unroll 1
        for (int t = 0; t < NN; ++t) {
            float usel = (t & 1) ? uu.y : uu.x;
            float ut = __int_as_float(__builtin_amdgcn_readlane(__float_as_int(usel), t >> 1));

            float incl = dpp_scan_add(e0 + e1);
            float T = bcast63(incl);
            float thr = ut * T;
            float cum1 = incl, cum0 = incl - e1;

            bool a0 = (e0 != 0.0f), a1 = (e1 != 0.0f);
            bool c0 = a0 && (cum0 >= thr);
            bool c1 = a1 && (cum1 >= thr);
            float mg = DELTA * T;
            bool amb = (a0 && fabsf(cum0 - thr) <= mg) || (a1 && fabsf(cum1 - thr) <= mg);

            unsigned long long b0 = __ballot(c0), b1 = __ballot(c1);
            unsigned long long ba = __ballot(amb);

            int idx;
            if (__builtin_expect(ba != 0ull, 0)) {
                // ---- slow path: bit-faithful numpy-f32 emulation ----
                int lastActive = mhi ? (127 - __clzll(mhi)) : (63 - __clzll(mlo));
                float l0 = 1.0f - rm0, l1v = 1.0f - rm1;
                float lvi = fmaxf(a0 ? l0 : NEGF, a1 ? l1v : NEGF);
                float lv = bcast63(dpp_scan_max(lvi));
                float f0 = a0 ? expf(l0 - lv) : 0.0f;
                float f1 = a1 ? expf(l1v - lv) : 0.0f;
                // numpy pairwise-8 accumulator sum
                int mm = lane & 3;
                float s0 = __shfl(f0, mm), s1 = __shfl(f1, mm);
                #pragma unroll
                for (int k2 = 1; k2 < 16; ++k2) {
                    s0 += __shfl(f0, mm + 4 * k2);
                    s1 += __shfl(f1, mm + 4 * k2);
                }
                float A00 = __shfl(s0, 0), A01 = __shfl(s0, 1), A02 = __shfl(s0, 2), A03 = __shfl(s0, 3);
                float A10 = __shfl(s1, 0), A11 = __shfl(s1, 1), A12 = __shfl(s1, 2), A13 = __shfl(s1, 3);
                float tot = ((A00 + A10) + (A01 + A11)) + ((A02 + A12) + (A03 + A13));
                float s = 0.0f;
                int pick = -1;
                for (int j = 0; j < NN; ++j) {
                    float ej = __shfl((j & 1) ? f1 : f0, j >> 1);
                    float pj = ej / tot;
                    s += pj;
                    bool aj = (j < 64) ? ((mlo >> j) & 1ull) : ((mhi >> (j - 64)) & 1ull);
                    if (pick < 0 && aj && s >= ut) pick = j;
                }
                idx = (pick >= 0) ? pick : lastActive;
            } else {
                // a cond-true row always exists (last active row has cum == T >= thr)
                int f0i = b0 ? 2 * (__ffsll(b0) - 1) : 999;
                int f1i = b1 ? 2 * (__ffsll(b1) - 1) + 1 : 999;
                idx = min(f0i, f1i);
            }

            if (lane == 0) ordS[wv * NN + t] = idx;

            if (idx < 64) mlo &= ~(1ull << idx);
            else          mhi &= ~(1ull << (idx - 64));
            if (idx == i0) e0 = 0.0f;
            if (idx == i1) e1 = 0.0f;

            // rescan rows whose tracked max-holder column was removed
            // (single combined loop; rescans are independent, order-free)
            unsigned long long r0 = __ballot((e0 != 0.0f) && (rc0 == idx));
            unsigned long long r1 = __ballot((e1 != 0.0f) && (rc1 == idx));

            while (r0 | r1) {
                int L, par;
                if (r0) { L = __ffsll(r0) - 1; r0 &= r0 - 1; par = 0; }
                else    { L = __ffsll(r1) - 1; r1 &= r1 - 1; par = 1; }
                int row = 2 * L + par, xm = row & 31;
                float v0 = ((mlo >> lane) & 1) ? S[row * 128 + (lane ^ xm)] : NEGF;
                float v1 = ((mhi >> lane) & 1) ? S[row * 128 + ((lane + 64) ^ xm)] : NEGF;
                float m2 = bcast63(dpp_scan_max(fmaxf(v0, v1)));
                unsigned long long h0 = __ballot(v0 == m2);
                unsigned long long h1 = __ballot(v1 == m2);
                int nc = h0 ? (__ffsll(h0) - 1) : (64 + __ffsll(h1) - 1);
                if (par == 0) {
                    if (lane == L) { rm0 = m2; rc0 = nc; e0 = __expf(1.0f - m2); }
                } else {
                    if (lane == L) { rm1 = m2; rc1 = nc; e1 = __expf(1.0f - m2); }
                }
            }
        }
    }
    __syncthreads();

    // ---- write order output (coalesced) ----
    #pragma unroll
    for (int k = 0; k < 2; ++k) {
        int i = k * 256 + tid;
        int dg = blockIdx.x * 4 + (i >> 7);
        if (dg < D) orderF[(size_t)blockIdx.x * 512 + i] = (float)ordS[i];
    }

    // ---- build tail: 5 iterations, dump(w-1) overlapped under compute(w) --
    for (int w = 0; w <= 4; ++w) {
        if (w >= 1) {
            const int dPrev = blockIdx.x * 4 + (w - 1);
            if (dPrev < D) {
                const unsigned char* Tp = T8[w - 1];
                float* od = out0 + (size_t)dPrev * NN * NN;
                #pragma unroll
                for (int k = 0; k < 16; ++k) {
                    int base = k * 1024 + tid * 4;
                    int i = base >> 7, j = base & 127;
                    const uchar4 v = *reinterpret_cast<const uchar4*>(&Tp[i * NN + (j ^ (i & 124))]);
                    float4 o;
                    o.x = (float)v.x; o.y = (float)v.y; o.z = (float)v.z; o.w = (float)v.w;
                    *reinterpret_cast<float4*>(&od[base]) = o;
                }
            }
        }
        if (w < 4) {
            const int d = blockIdx.x * 4 + w;
            if (d < D) {
                unsigned char* Tw = T8[w];
                const float* G0 = G + (size_t)d * 2 * NN * NN;
                const float* G1 = G0 + NN * NN;
                const int* pw = &ordS[w * NN];

                for (int base = 0; base < 8192; base += 2048) {
                    float u0[8], u1[8], sg[8];
                    int rr8[8], cc8[8];
                    bool ok[8];
                    #pragma unroll
                    for (int j = 0; j < 8; ++j) {
                        int k = base + j * 256 + tid;
                        ok[j] = (k < 8128);
                        if (ok[j]) {
                            float fr = sqrtf(8.0f * (float)k + 1.0f);
                            int r = (int)((1.0f + fr) * 0.5f);
                            if (r * (r - 1) / 2 > k) --r;
                            if ((r + 1) * r / 2 <= k) ++r;
                            int c = k - r * (r - 1) / 2;
                            rr8[j] = r; cc8[j] = c;
                            int idx = r * NN + c;
                            u0[j] = G0[idx];
                            u1[j] = G1[idx];
                            int prr = pw[r], pcc = pw[c];
                            sg[j] = S[prr * 128 + (pcc ^ (prr & 31))];
                        }
                    }
                    #pragma unroll
                    for (int j = 0; j < 8; ++j) {
                        if (ok[j]) {
                            int prr = pw[rr8[j]], pcc = pw[cc8[j]];
                            // la+g0 >= l1+g1  <=>  sg*B >= (1-sg)*A
                            float A = -__logf(u0[j] + 1e-10f) + 1e-10f;
                            float B = -__logf(u1[j] + 1e-10f) + 1e-10f;
                            Tw[pcc * NN + (prr ^ (pcc & 124))] = (sg[j] * B >= (1.0f - sg[j]) * A) ? 1 : 0;
                        }
                    }
                }
            }
        }
        __syncthreads();
    }
}

extern "C" void kernel_launch(void* const* d_in, const int* in_sizes, int n_in,
                              void* d_out, int out_size, void* d_ws, size_t ws_size,
                              hipStream_t stream) {
    const float* P        = (const float*)d_in[0];
    const float* uniforms = (const float*)d_in[1];
    const float* G        = (const float*)d_in[2];
    const int D = in_sizes[1] / NN;

    float* out0   = (float*)d_out;
    float* orderF = out0 + (size_t)D * NN * NN;
    float* sigS   = (float*)d_ws;   // 64KB

    k_sig<<<(NN * NN + 255) / 256, 256, 0, stream>>>(P, sigS);
    k_fused<<<(D + 3) / 4, 256, 0, stream>>>(sigS, uniforms, G, out0, orderF, D);
}

// Round 15
// 146.595 us; speedup vs baseline: 1.2629x; 1.0483x over previous
//
#include <hip/hip_runtime.h>

#define NN 128
#define NEGF -1e30f
#define DELTA 1.5e-5f

// ---- wave64 inclusive prefix-sum via DPP (6 dependent VALU ops) ----
__device__ __forceinline__ float dpp_scan_add(float x) {
    int v;
    v = __builtin_amdgcn_update_dpp(0, __float_as_int(x), 0x111, 0xf, 0xf, true);
    x += __int_as_float(v);
    v = __builtin_amdgcn_update_dpp(0, __float_as_int(x), 0x112, 0xf, 0xf, true);
    x += __int_as_float(v);
    v = __builtin_amdgcn_update_dpp(0, __float_as_int(x), 0x114, 0xf, 0xf, true);
    x += __int_as_float(v);
    v = __builtin_amdgcn_update_dpp(0, __float_as_int(x), 0x118, 0xf, 0xf, true);
    x += __int_as_float(v);
    v = __builtin_amdgcn_update_dpp(0, __float_as_int(x), 0x142, 0xa, 0xf, true);
    x += __int_as_float(v);
    v = __builtin_amdgcn_update_dpp(0, __float_as_int(x), 0x143, 0xc, 0xf, true);
    x += __int_as_float(v);
    return x;   // lane l holds sum over lanes 0..l
}

// ---- wave64 max-scan via DPP; lane 63 holds the global max ----
__device__ __forceinline__ float dpp_scan_max(float x) {
    const int negi = __float_as_int(NEGF);
    int v;
    v = __builtin_amdgcn_update_dpp(negi, __float_as_int(x), 0x111, 0xf, 0xf, false);
    x = fmaxf(x, __int_as_float(v));
    v = __builtin_amdgcn_update_dpp(negi, __float_as_int(x), 0x112, 0xf, 0xf, false);
    x = fmaxf(x, __int_as_float(v));
    v = __builtin_amdgcn_update_dpp(negi, __float_as_int(x), 0x114, 0xf, 0xf, false);
    x = fmaxf(x, __int_as_float(v));
    v = __builtin_amdgcn_update_dpp(negi, __float_as_int(x), 0x118, 0xf, 0xf, false);
    x = fmaxf(x, __int_as_float(v));
    v = __builtin_amdgcn_update_dpp(negi, __float_as_int(x), 0x142, 0xa, 0xf, false);
    x = fmaxf(x, __int_as_float(v));
    v = __builtin_amdgcn_update_dpp(negi, __float_as_int(x), 0x143, 0xc, 0xf, false);
    x = fmaxf(x, __int_as_float(v));
    return x;
}

__device__ __forceinline__ float bcast63(float x) {
    return __int_as_float(__builtin_amdgcn_readlane(__float_as_int(x), 63));
}

// ---------------- K0: sigmoid table ----------------
__global__ void k_sig(const float* __restrict__ P, float* __restrict__ sigS) {
    int i = blockIdx.x * blockDim.x + threadIdx.x;
    if (i < NN * NN) {
        double p = (double)P[i];
        sigS[i] = (float)(1.0 / (1.0 + exp(-p)));
    }
}

// -------- fused: order sampling (R4-exact) + pipelined build tail ----------
// LDS swizzle: S[r][c] lives at S[r*128 + (c ^ (r & 31))]
__launch_bounds__(256)
__global__ void k_fused(const float* __restrict__ sigS,
                        const float* __restrict__ uniforms,
                        const float* __restrict__ G,
                        float* __restrict__ out0,
                        float* __restrict__ orderF, int D) {
    __shared__ float S[NN * NN];                // 64KB swizzled sigmoid table
    __shared__ unsigned char T8[4][NN * NN];    // 64KB: one 16KB tile per dag
    __shared__ int ordS[4 * NN];                // 2KB: per-wave order
    const int tid = threadIdx.x;

    // stage sigP -> LDS (swizzled) and zero all 4 tiles; ONE barrier
    for (int k = 0; k < 16; ++k) {
        int idx4 = (k * 256 + tid) * 4;
        int r = idx4 >> 7, cb = idx4 & 127;
        float4 v = *reinterpret_cast<const float4*>(&sigS[idx4]);
        int x = r & 31;
        float4 w;
        switch (x & 3) {
            case 0: w = v; break;
            case 1: w = make_float4(v.y, v.x, v.w, v.z); break;
            case 2: w = make_float4(v.z, v.w, v.x, v.y); break;
            default: w = make_float4(v.w, v.z, v.y, v.x); break;
        }
        *reinterpret_cast<float4*>(&S[r * 128 + ((cb ^ x) & ~3)]) = w;
    }
    {
        uint4 z = make_uint4(0, 0, 0, 0);
        #pragma unroll
        for (int k = 0; k < 16; ++k)
            reinterpret_cast<uint4*>(&T8[0][0])[k * 256 + tid] = z;
    }
    __syncthreads();

    const int lane = tid & 63;
    const int wv = tid >> 6;
    const int dag = blockIdx.x * 4 + wv;

    if (dag < D) {
        const int i0 = 2 * lane, i1 = 2 * lane + 1;
        const int x0 = i0 & 31, x1 = i1 & 31;
        const int q0 = x0 & 3, q1 = x1 & 3;
        float2 uu = *reinterpret_cast<const float2*>(&uniforms[dag * NN + i0]);

        unsigned long long mlo = ~0ull, mhi = ~0ull;

        // initial row max + holder column
        float rm0 = NEGF, rm1 = NEGF;
        int rc0 = 0, rc1 = 0;
        for (int k = 0; k < 32; ++k) {
            int cb = 4 * ((k + lane) & 31);
            float4 a = *reinterpret_cast<const float4*>(&S[i0 * 128 + (cb ^ (x0 & ~3))]);
            float4 b = *reinterpret_cast<const float4*>(&S[i1 * 128 + (cb ^ (x1 & ~3))]);
            if (a.x > rm0) { rm0 = a.x; rc0 = cb | (0 ^ q0); }
            if (a.y > rm0) { rm0 = a.y; rc0 = cb | (1 ^ q0); }
            if (a.z > rm0) { rm0 = a.z; rc0 = cb | (2 ^ q0); }
            if (a.w > rm0) { rm0 = a.w; rc0 = cb | (3 ^ q0); }
            if (b.x > rm1) { rm1 = b.x; rc1 = cb | (0 ^ q1); }
            if (b.y > rm1) { rm1 = b.y; rc1 = cb | (1 ^ q1); }
            if (b.z > rm1) { rm1 = b.z; rc1 = cb | (2 ^ q1); }
            if (b.w > rm1) { rm1 = b.w; rc1 = cb | (3 ^ q1); }
        }

        float e0 = __expf(1.0f - rm0);   // 0 marks inactive row
        float e1 = __expf(1.0f - rm1);

        #pragma unroll 1
        for (int t = 0; t < NN; ++t) {
            float usel = (t & 1) ? uu.y : uu.x;
            float ut = __int_as_float(__builtin_amdgcn_readlane(__float_as_int(usel), t >> 1));

            float incl = dpp_scan_add(e0 + e1);
            float T = bcast63(incl);
            float thr = ut * T;
            float cum1 = incl, cum0 = incl - e1;

            bool a0 = (e0 != 0.0f), a1 = (e1 != 0.0f);
            bool c0 = a0 && (cum0 >= thr);
            bool c1 = a1 && (cum1 >= thr);
            float mg = DELTA * T;
            bool amb = (a0 && fabsf(cum0 - thr) <= mg) || (a1 && fabsf(cum1 - thr) <= mg);

            unsigned long long b0 = __ballot(c0), b1 = __ballot(c1);
            unsigned long long ba = __ballot(amb);
            int lastActive = mhi ? (127 - __clzll(mhi)) : (63 - __clzll(mlo));

            int idx;
            if (__builtin_expect(ba != 0ull, 0)) {
                // ---- slow path: bit-faithful numpy-f32 emulation ----
                float l0 = 1.0f - rm0, l1v = 1.0f - rm1;
                float lvi = fmaxf(a0 ? l0 : NEGF, a1 ? l1v : NEGF);
                float lv = bcast63(dpp_scan_max(lvi));
                float f0 = a0 ? expf(l0 - lv) : 0.0f;
                float f1 = a1 ? expf(l1v - lv) : 0.0f;
                // numpy pairwise-8 accumulator sum
                int mm = lane & 3;
                float s0 = __shfl(f0, mm), s1 = __shfl(f1, mm);
                #pragma unroll
                for (int k2 = 1; k2 < 16; ++k2) {
                    s0 += __shfl(f0, mm + 4 * k2);
                    s1 += __shfl(f1, mm + 4 * k2);
                }
                float A00 = __shfl(s0, 0), A01 = __shfl(s0, 1), A02 = __shfl(s0, 2), A03 = __shfl(s0, 3);
                float A10 = __shfl(s1, 0), A11 = __shfl(s1, 1), A12 = __shfl(s1, 2), A13 = __shfl(s1, 3);
                float tot = ((A00 + A10) + (A01 + A11)) + ((A02 + A12) + (A03 + A13));
                float s = 0.0f;
                int pick = -1;
                for (int j = 0; j < NN; ++j) {
                    float ej = __shfl((j & 1) ? f1 : f0, j >> 1);
                    float pj = ej / tot;
                    s += pj;
                    bool aj = (j < 64) ? ((mlo >> j) & 1ull) : ((mhi >> (j - 64)) & 1ull);
                    if (pick < 0 && aj && s >= ut) pick = j;
                }
                idx = (pick >= 0) ? pick : lastActive;
            } else {
                int f0i = b0 ? 2 * (__ffsll(b0) - 1) : 999;
                int f1i = b1 ? 2 * (__ffsll(b1) - 1) + 1 : 999;
                idx = min(f0i, f1i);
                if (idx == 999) idx = lastActive;
            }

            if (lane == 0) ordS[wv * NN + t] = idx;

            if (idx < 64) mlo &= ~(1ull << idx);
            else          mhi &= ~(1ull << (idx - 64));
            if (idx == i0) e0 = 0.0f;
            if (idx == i1) e1 = 0.0f;
            a0 = (e0 != 0.0f); a1 = (e1 != 0.0f);

            // rescan rows whose tracked max-holder column was removed
            unsigned long long r0 = __ballot(a0 && (rc0 == idx));
            unsigned long long r1 = __ballot(a1 && (rc1 == idx));

            while (r0) {
                int L = __ffsll(r0) - 1; r0 &= r0 - 1;
                int row = 2 * L, xm = row & 31;
                float v0 = ((mlo >> lane) & 1) ? S[row * 128 + (lane ^ xm)] : NEGF;
                float v1 = ((mhi >> lane) & 1) ? S[row * 128 + ((lane + 64) ^ xm)] : NEGF;
                float m2 = bcast63(dpp_scan_max(fmaxf(v0, v1)));
                unsigned long long h0 = __ballot(v0 == m2);
                unsigned long long h1 = __ballot(v1 == m2);
                int nc = h0 ? (__ffsll(h0) - 1) : (64 + __ffsll(h1) - 1);
                if (lane == L) { rm0 = m2; rc0 = nc; e0 = __expf(1.0f - m2); }
            }
            while (r1) {
                int L = __ffsll(r1) - 1; r1 &= r1 - 1;
                int row = 2 * L + 1, xm = row & 31;
                float v0 = ((mlo >> lane) & 1) ? S[row * 128 + (lane ^ xm)] : NEGF;
                float v1 = ((mhi >> lane) & 1) ? S[row * 128 + ((lane + 64) ^ xm)] : NEGF;
                float m2 = bcast63(dpp_scan_max(fmaxf(v0, v1)));
                unsigned long long h0 = __ballot(v0 == m2);
                unsigned long long h1 = __ballot(v1 == m2);
                int nc = h0 ? (__ffsll(h0) - 1) : (64 + __ffsll(h1) - 1);
                if (lane == L) { rm1 = m2; rc1 = nc; e1 = __expf(1.0f - m2); }
            }
        }
    }
    __syncthreads();

    // ---- write order output (coalesced) ----
    #pragma unroll
    for (int k = 0; k < 2; ++k) {
        int i = k * 256 + tid;
        int dg = blockIdx.x * 4 + (i >> 7);
        if (dg < D) orderF[(size_t)blockIdx.x * 512 + i] = (float)ordS[i];
    }

    // ---- build tail: 5 iterations, dump(w-1) overlapped under compute(w) --
    for (int w = 0; w <= 4; ++w) {
        // dump tile w-1 (written before the previous barrier)
        if (w >= 1) {
            const int dPrev = blockIdx.x * 4 + (w - 1);
            if (dPrev < D) {
                const unsigned char* Tp = T8[w - 1];
                float* od = out0 + (size_t)dPrev * NN * NN;
                #pragma unroll
                for (int k = 0; k < 16; ++k) {
                    int base = k * 1024 + tid * 4;
                    int i = base >> 7, j = base & 127;
                    const uchar4 v = *reinterpret_cast<const uchar4*>(&Tp[i * NN + (j ^ (i & 124))]);
                    float4 o;
                    o.x = (float)v.x; o.y = (float)v.y; o.z = (float)v.z; o.w = (float)v.w;
                    *reinterpret_cast<float4*>(&od[base]) = o;
                }
            }
        }
        // compute tile w
        if (w < 4) {
            const int d = blockIdx.x * 4 + w;
            if (d < D) {
                unsigned char* Tw = T8[w];
                const float* G0 = G + (size_t)d * 2 * NN * NN;
                const float* G1 = G0 + NN * NN;
                const int* pw = &ordS[w * NN];

                for (int base = 0; base < 8192; base += 2048) {
                    float u0[8], u1[8], sg[8];
                    int rr8[8], cc8[8];
                    bool ok[8];
                    #pragma unroll
                    for (int j = 0; j < 8; ++j) {
                        int k = base + j * 256 + tid;
                        ok[j] = (k < 8128);
                        if (ok[j]) {
                            float fr = sqrtf(8.0f * (float)k + 1.0f);
                            int r = (int)((1.0f + fr) * 0.5f);
                            if (r * (r - 1) / 2 > k) --r;
                            if ((r + 1) * r / 2 <= k) ++r;
                            int c = k - r * (r - 1) / 2;
                            rr8[j] = r; cc8[j] = c;
                            int idx = r * NN + c;
                            u0[j] = G0[idx];
                            u1[j] = G1[idx];
                            int prr = pw[r], pcc = pw[c];
                            sg[j] = S[prr * 128 + (pcc ^ (prr & 31))];
                        }
                    }
                    #pragma unroll
                    for (int j = 0; j < 8; ++j) {
                        if (ok[j]) {
                            int prr = pw[rr8[j]], pcc = pw[cc8[j]];
                            // la+g0 >= l1+g1  <=>  sg*B >= (1-sg)*A
                            float A = -__logf(u0[j] + 1e-10f) + 1e-10f;
                            float B = -__logf(u1[j] + 1e-10f) + 1e-10f;
                            Tw[pcc * NN + (prr ^ (pcc & 124))] = (sg[j] * B >= (1.0f - sg[j]) * A) ? 1 : 0;
                        }
                    }
                }
            }
        }
        __syncthreads();
    }
}

extern "C" void kernel_launch(void* const* d_in, const int* in_sizes, int n_in,
                              void* d_out, int out_size, void* d_ws, size_t ws_size,
                              hipStream_t stream) {
    const float* P        = (const float*)d_in[0];
    const float* uniforms = (const float*)d_in[1];
    const float* G        = (const float*)d_in[2];
    const int D = in_sizes[1] / NN;

    float* out0   = (float*)d_out;
    float* orderF = out0 + (size_t)D * NN * NN;
    float* sigS   = (float*)d_ws;   // 64KB

    k_sig<<<(NN * NN + 255) / 256, 256, 0, stream>>>(P, sigS);
    k_fused<<<(D + 3) / 4, 256, 0, stream>>>(sigS, uniforms, G, out0, orderF, D);
}